// Round 9
// baseline (355.850 us; speedup 1.0000x reference)
//
#include <hip/hip_runtime.h>
#include <hip/hip_bf16.h>

#define N_NODES 100000
#define IN_F 256
#define HID_F 128
#define OUT_F 32
#define NBUCK 391                  // buckets of 256 rows (row >> 8)
#define BCAP  5120                 // per-bucket staging capacity (mean 4092)
#define ACHUNK 4096                // edges per bucketize block
#define NCHUNKS ((1600000 + ACHUNK - 1) / ACHUNK)   // 391 for E=1.6M
#define GEMM1_BLOCKS ((N_NODES + 127) / 128)        // 782

typedef __bf16 bf16x8 __attribute__((ext_vector_type(8)));
typedef __bf16 bf16x4 __attribute__((ext_vector_type(4)));
typedef __bf16 bf16x2 __attribute__((ext_vector_type(2)));
typedef float  f32x4  __attribute__((ext_vector_type(4)));

// ---------------- W1 [256 k][128 n] f32 -> W1T [128 n][256 k] bf16 ----------------
__global__ void cvt_w1t_kernel(const float* __restrict__ W1, __bf16* __restrict__ W1T) {
    int i = blockIdx.x * 256 + threadIdx.x;      // i = n*256 + k
    if (i >= IN_F * HID_F) return;
    int n = i >> 8, k = i & 255;
    W1T[i] = (__bf16)W1[k * HID_F + n];
}

// ---------------- bucketize body (stage A of CSR build) ----------------
// smem: int2 lcv[4096] | lcnt/loff/lcur/gbase[NBUCK] | psum[256] = 40048 B
__device__ __forceinline__
void bucketize_body(char* smem, int blk,
                    const int* __restrict__ rows, const int* __restrict__ cols,
                    const float* __restrict__ vals, int* __restrict__ gcnt,
                    int2* __restrict__ staged, int E) {
    int2* lcv  = (int2*)smem;
    int* lcnt  = (int*)(smem + ACHUNK * 8);
    int* loff  = lcnt + NBUCK;
    int* lcur  = loff + NBUCK;
    int* gbase = lcur + NBUCK;
    int* psum  = gbase + NBUCK;

    const int t    = threadIdx.x;
    const int base = blk * ACHUNK;

    for (int b = t; b < NBUCK; b += 256) lcnt[b] = 0;
    __syncthreads();

    int myrow[16];
#pragma unroll
    for (int i = 0; i < 16; ++i) {
        int e = base + t + i * 256;
        int r = (e < E) ? rows[e] : -1;
        myrow[i] = r;
        if (r >= 0) atomicAdd(&lcnt[r >> 8], 1);
    }
    __syncthreads();

    int s0 = (t * 2     < NBUCK) ? lcnt[t * 2]     : 0;
    int s1 = (t * 2 + 1 < NBUCK) ? lcnt[t * 2 + 1] : 0;
    int local = s0 + s1;
    psum[t] = local;
    __syncthreads();
    for (int off = 1; off < 256; off <<= 1) {
        int v = (t >= off) ? psum[t - off] : 0;
        __syncthreads();
        psum[t] += v;
        __syncthreads();
    }
    int excl = psum[t] - local;
    if (t * 2     < NBUCK) { loff[t * 2]     = excl;      lcur[t * 2]     = excl; }
    if (t * 2 + 1 < NBUCK) { loff[t * 2 + 1] = excl + s0; lcur[t * 2 + 1] = excl + s0; }
    __syncthreads();

#pragma unroll
    for (int i = 0; i < 16; ++i) {
        int r = myrow[i];
        if (r >= 0) {
            int e = base + t + i * 256;
            int posl = atomicAdd(&lcur[r >> 8], 1);
            lcv[posl] = make_int2(cols[e] | ((r & 255) << 20), __float_as_int(vals[e]));
        }
    }
    __syncthreads();

    for (int b = t; b < NBUCK; b += 256) {
        int c = lcnt[b];
        gbase[b] = c ? atomicAdd(&gcnt[b], c) : 0;
    }
    __syncthreads();

    int total = loff[NBUCK - 1] + lcnt[NBUCK - 1];
    for (int i = t; i < total; i += 256) {
        int lo = 0, hi = NBUCK - 1;
        while (lo < hi) {
            int mid = (lo + hi + 1) >> 1;
            if (loff[mid] <= i) lo = mid; else hi = mid - 1;
        }
        int idx = gbase[lo] + (i - loff[lo]);
        if (idx < BCAP)
            staged[(size_t)lo * BCAP + idx] = lcv[i];
    }
}

// ---------------- gemm1 body (MFMA): xw_bf16 = bf16(x) @ bf16(W1) ----------------
// Round-3/4 proven structure: quarter-K tiles, both operands in LDS, [76] pad.
__device__ __forceinline__
void gemm1_body(char* smem, int blk,
                const float* __restrict__ x, const __bf16* __restrict__ W1T,
                __bf16* __restrict__ xw) {
    __bf16 (*Xs)[76] = (__bf16 (*)[76])smem;
    __bf16 (*Bs)[76] = (__bf16 (*)[76])(smem + 19456);
    __bf16 (*Ls)[136] = (__bf16 (*)[136])smem;   // epilogue tile (34816 B)

    const int r0   = blk * 128;
    const int t    = threadIdx.x;
    const int wv   = t >> 6;
    const int lane = t & 63;
    const int quad = lane >> 4;
    const int l15  = lane & 15;

    f32x4 acc[2][8];
#pragma unroll
    for (int rt = 0; rt < 2; ++rt)
#pragma unroll
        for (int nt = 0; nt < 8; ++nt)
            acc[rt][nt] = (f32x4){0.f, 0.f, 0.f, 0.f};

    const int srow = t >> 3;          // 0..31
    const int soct = t & 7;           // 0..7

    for (int q = 0; q < 4; ++q) {
        const int kq = q * 64;
#pragma unroll
        for (int j = 0; j < 4; ++j) {
            int row = j * 32 + srow;
            int gm = r0 + row;
            if (gm > N_NODES - 1) gm = N_NODES - 1;
            const float* xp = x + (size_t)gm * IN_F + kq + soct * 8;
            float4 f0 = *(const float4*)xp;
            float4 f1 = *(const float4*)(xp + 4);
            bf16x8 v = { (__bf16)f0.x, (__bf16)f0.y, (__bf16)f0.z, (__bf16)f0.w,
                         (__bf16)f1.x, (__bf16)f1.y, (__bf16)f1.z, (__bf16)f1.w };
            *(bf16x8*)(&Xs[row][soct * 8]) = v;
        }
#pragma unroll
        for (int i = 0; i < 4; ++i) {
            int idx = t + i * 256;            // 0..1023
            int n = idx >> 3, kc = idx & 7;
            bf16x8 w = *(const bf16x8*)(W1T + n * 256 + kq + kc * 8);
            *(bf16x8*)(&Bs[n][kc * 8]) = w;
        }
        __syncthreads();

#pragma unroll
        for (int kt = 0; kt < 2; ++kt) {
            const int k0 = kt * 32;
            bf16x8 a[2];
#pragma unroll
            for (int rt = 0; rt < 2; ++rt)
                a[rt] = *(const bf16x8*)(&Xs[wv * 32 + rt * 16 + l15][k0 + quad * 8]);
            bf16x8 b[8];
#pragma unroll
            for (int nt = 0; nt < 8; ++nt)
                b[nt] = *(const bf16x8*)(&Bs[nt * 16 + l15][k0 + quad * 8]);
#pragma unroll
            for (int rt = 0; rt < 2; ++rt)
#pragma unroll
                for (int nt = 0; nt < 8; ++nt)
                    acc[rt][nt] = __builtin_amdgcn_mfma_f32_16x16x32_bf16(
                        a[rt], b[nt], acc[rt][nt], 0, 0, 0);
        }
        __syncthreads();
    }

    // ---- epilogue: acc -> LDS (bf16) -> coalesced global stores ----
#pragma unroll
    for (int rt = 0; rt < 2; ++rt)
#pragma unroll
        for (int nt = 0; nt < 8; ++nt)
#pragma unroll
            for (int reg = 0; reg < 4; ++reg)
                Ls[wv * 32 + rt * 16 + quad * 4 + reg][nt * 16 + l15] =
                    (__bf16)acc[rt][nt][reg];
    __syncthreads();

#pragma unroll
    for (int i = 0; i < 8; ++i) {
        int id = i * 256 + t;                 // 0..2047
        int row = id >> 4, cc = id & 15;
        int g = r0 + row;
        if (g < N_NODES) {
            bf16x8 v = *(const bf16x8*)(&Ls[row][cc * 8]);
            *(bf16x8*)(xw + (size_t)g * HID_F + cc * 8) = v;
        }
    }
}

// ---------------- fused: bucketize (blocks 0..NCHUNKS-1) + gemm1 (rest) ----------------
__global__ __launch_bounds__(256, 4)
void fused_gemm1_bucketize_kernel(const float* __restrict__ x,
                                  const __bf16* __restrict__ W1T,
                                  __bf16* __restrict__ xw,
                                  const int* __restrict__ rows,
                                  const int* __restrict__ cols,
                                  const float* __restrict__ vals,
                                  int* __restrict__ gcnt,
                                  int2* __restrict__ staged, int E) {
    __shared__ __align__(16) char smem[40448];   // 4 blocks/CU
    if (blockIdx.x < NCHUNKS)
        bucketize_body(smem, blockIdx.x, rows, cols, vals, gcnt, staged, E);
    else
        gemm1_body(smem, blockIdx.x - NCHUNKS, x, W1T, xw);
}

// ---- per-bucket CSR finalize: inline scan of clamped gcnt + LDS counting sort ----
__global__ __launch_bounds__(256)
void bucket_csr_kernel(const int* __restrict__ gcnt,
                       const int2* __restrict__ staged,
                       int* __restrict__ row_ptr, int2* __restrict__ pedge) {
    __shared__ int2 lcv[BCAP];        // 40960 B
    __shared__ int lcnt[256], loff[256], lcur[256];
    __shared__ int psum[256];
    __shared__ int boff[NBUCK + 1];

    const int b = blockIdx.x;
    const int t = threadIdx.x;

    int c0 = (t * 2     < NBUCK) ? min(gcnt[t * 2],     BCAP) : 0;
    int c1 = (t * 2 + 1 < NBUCK) ? min(gcnt[t * 2 + 1], BCAP) : 0;
    int local = c0 + c1;
    psum[t] = local;
    __syncthreads();
    for (int off = 1; off < 256; off <<= 1) {
        int v = (t >= off) ? psum[t - off] : 0;
        __syncthreads();
        psum[t] += v;
        __syncthreads();
    }
    int excl = psum[t] - local;
    if (t * 2     < NBUCK)  boff[t * 2]     = excl;
    if (t * 2 + 1 <= NBUCK) boff[t * 2 + 1] = excl + c0;
    __syncthreads();

    int n = gcnt[b]; if (n > BCAP) n = BCAP;
    const int2* sp = staged + (size_t)b * BCAP;
    const int base = boff[b];

    if (b == NBUCK - 1 && t == 0) row_ptr[N_NODES] = boff[NBUCK];

    lcnt[t] = 0;
    __syncthreads();
    for (int i = t; i < n; i += 256) {
        int2 v = sp[i];
        lcv[i] = v;
        atomicAdd(&lcnt[(v.x >> 20) & 255], 1);
    }
    __syncthreads();

    int v = lcnt[t];
    loff[t] = v;
    __syncthreads();
    for (int off = 1; off < 256; off <<= 1) {
        int u = (t >= off) ? loff[t - off] : 0;
        __syncthreads();
        loff[t] += u;
        __syncthreads();
    }
    int excl2 = loff[t] - v;
    lcur[t] = excl2;
    __syncthreads();

    int row = (b << 8) + t;
    if (row < N_NODES) row_ptr[row] = base + excl2;

    for (int i = t; i < n; i += 256) {
        int2 cv = lcv[i];
        int r = (cv.x >> 20) & 255;
        int pos = atomicAdd(&lcur[r], 1);         // LDS cursor
        pedge[base + pos] = make_int2(cv.x & 0xFFFFF, cv.y);
    }
}

// ------- SpMM layer 1 + GEMM2 fused: hw = (relu(A @ xw)) @ bf16(W2) -------
// VALU-bound rewrite (round-7 counters: VALUBusy 85%, 9.6M bank conflicts):
//  * 2 edges per wave-round: lane = (edge slot half=lane>>5, feat-quad q=lane&31),
//    each lane gathers bf16x4 (32 lanes x 8 B = one full 256-B row per half-wave).
//    Amortizes clamp/address/pedge over 2 edges: ~7 VALU/edge vs ~15.
//  * h kept in f32 LDS (no bf16 round-trip, no cvt on h side of mini-GEMM).
//  * W2T pad 132 (stride 66 words === 2 mod 32 -> 4-way max, was 8-way at 136).
__global__ __launch_bounds__(256)
void spmm1_gemm2_kernel(const int* __restrict__ row_ptr,
                        const int2* __restrict__ pedge,
                        const __bf16* __restrict__ src,
                        const float* __restrict__ W2,
                        __bf16* __restrict__ hw) {
    __shared__ __bf16 W2T[32][132];               // [out o][k] bf16
    __shared__ __align__(16) float hs[4][128];    // per-wave h row, f32

    const int t    = threadIdx.x;
    const int wv   = t >> 6;
    const int lane = t & 63;
    const int half = lane >> 5;     // edge slot within a round
    const int q    = lane & 31;     // feat quad: feats 4q..4q+3

    // stage W2T: consecutive lanes read consecutive W2 elements (coalesced)
    for (int i = t; i < 32 * 128; i += 256) {
        int o = i & 31, k = i >> 5;
        W2T[o][k] = (__bf16)W2[i];
    }
    __syncthreads();

    const int row = __builtin_amdgcn_readfirstlane(blockIdx.x * 4 + wv);
    const int e0 = row_ptr[row];
    const int e1 = row_ptr[row + 1];

    const __bf16* srcq = src + q * 4;

    float a0 = 0.f, a1 = 0.f, a2 = 0.f, a3 = 0.f;
    for (int e = e0; e < e1; e += 8) {
#pragma unroll
        for (int r = 0; r < 4; ++r) {
            int ee = e + r * 2 + half;
            int ec = (ee < e1) ? ee : e1 - 1;
            int2 pp = pedge[ec];
            float v = (ee < e1) ? __int_as_float(pp.y) : 0.f;
            bf16x4 s = *(const bf16x4*)(srcq + ((size_t)(unsigned)pp.x << 7));
            a0 += v * (float)s[0];
            a1 += v * (float)s[1];
            a2 += v * (float)s[2];
            a3 += v * (float)s[3];
        }
    }
    // combine the two edge slots; lanes 0..31 then hold the full row
    a0 += __shfl_xor(a0, 32);
    a1 += __shfl_xor(a1, 32);
    a2 += __shfl_xor(a2, 32);
    a3 += __shfl_xor(a3, 32);
    if (half == 0) {
        f32x4 hv = { fmaxf(a0, 0.f), fmaxf(a1, 0.f),
                     fmaxf(a2, 0.f), fmaxf(a3, 0.f) };      // fused relu
        *(f32x4*)&hs[wv][q * 4] = hv;
    }
    __syncthreads();

    // ---- mini-GEMM: hw[row][o] = sum_k h[k] * W2[k][o]; lane o = q, k-half = half
    const int kh = half * 64;
    float s = 0.f;
#pragma unroll
    for (int kk = 0; kk < 64; kk += 4) {
        f32x4  hv = *(const f32x4*)&hs[wv][kh + kk];        // broadcast read
        bf16x4 w4 = *(const bf16x4*)&W2T[q][kh + kk];
        s += hv[0] * (float)w4[0] + hv[1] * (float)w4[1]
           + hv[2] * (float)w4[2] + hv[3] * (float)w4[3];
    }
    s += __shfl_xor(s, 32);
    if (half == 0)
        hw[(size_t)row * OUT_F + q] = (__bf16)s;
}

// ---------------- SpMM layer 2: out_f32 = A @ hw_bf16 ----------------
__global__ __launch_bounds__(256)
void spmm2_kernel(const int* __restrict__ row_ptr,
                  const int2* __restrict__ pedge,
                  const __bf16* __restrict__ src,
                  float* __restrict__ dst) {
    long long gid = (long long)blockIdx.x * 256 + threadIdx.x;
    int row  = (int)(gid >> 4);
    int lane = (int)(gid & 15);
    if (row >= N_NODES) return;

    const int e0 = row_ptr[row];
    const int e1 = row_ptr[row + 1];

    float a0 = 0.f, a1 = 0.f;
    for (int e = e0; e < e1; e += 8) {
        int2 p[8];
#pragma unroll
        for (int j = 0; j < 8; ++j) {
            int ee = e + j;
            if (ee >= e1) ee = e1 - 1;
            p[j] = pedge[ee];
            if (e + j >= e1) p[j].y = 0;
        }
        bf16x2 s[8];
#pragma unroll
        for (int j = 0; j < 8; ++j)
            s[j] = ((const bf16x2*)(src + (size_t)p[j].x * OUT_F))[lane];
#pragma unroll
        for (int j = 0; j < 8; ++j) {
            float v = __int_as_float(p[j].y);
            a0 += v * (float)s[j].x;
            a1 += v * (float)s[j].y;
        }
    }
    ((float2*)(dst + (size_t)row * OUT_F))[lane] = make_float2(a0, a1);
}

extern "C" void kernel_launch(void* const* d_in, const int* in_sizes, int n_in,
                              void* d_out, int out_size, void* d_ws, size_t ws_size,
                              hipStream_t stream) {
    const float* x        = (const float*)d_in[0];
    const int*   adj_rows = (const int*)d_in[1];
    const int*   adj_cols = (const int*)d_in[2];
    const float* adj_vals = (const float*)d_in[3];
    const float* W1       = (const float*)d_in[4];
    const float* W2       = (const float*)d_in[5];
    float*       out      = (float*)d_out;
    const int E = in_sizes[1];

    char* p = (char*)d_ws;
    __bf16* W1T  = (__bf16*)p;  p += (size_t)IN_F * HID_F * sizeof(__bf16);     // 64 KB
    __bf16* xw   = (__bf16*)p;  p += (size_t)N_NODES * HID_F * sizeof(__bf16);  // 25.6 MB
    __bf16* hw   = (__bf16*)p;  p += (size_t)N_NODES * OUT_F * sizeof(__bf16);  // 6.4 MB
    int*   row_ptr = (int*)p;   p += (size_t)(N_NODES + 1) * sizeof(int);
    int*   gcnt    = (int*)p;   p += ((NBUCK + 255) & ~255) * sizeof(int);
    p = (char*)(((uintptr_t)p + 15) & ~(uintptr_t)15);
    int2*  pedge   = (int2*)p;  p += (size_t)E * sizeof(int2);                  // 12.8 MB
    p = (char*)(((uintptr_t)p + 15) & ~(uintptr_t)15);
    int2*  staged  = (int2*)p;  p += (size_t)NBUCK * BCAP * sizeof(int2);       // 16.0 MB

    // ---- prep ----
    hipMemsetAsync(gcnt, 0, (size_t)NBUCK * sizeof(int), stream);
    cvt_w1t_kernel<<<(IN_F * HID_F + 255) / 256, 256, 0, stream>>>(W1, W1T);

    // ---- fused: CSR stage-A (391 blocks) + gemm1 (782 blocks) ----
    fused_gemm1_bucketize_kernel<<<NCHUNKS + GEMM1_BLOCKS, 256, 0, stream>>>(
        x, W1T, xw, adj_rows, adj_cols, adj_vals, gcnt, staged, E);

    // ---- CSR finalize (scan fused into bucket_csr) ----
    bucket_csr_kernel<<<NBUCK, 256, 0, stream>>>(gcnt, staged, row_ptr, pedge);

    // ---- layer 1 aggregate + layer-2 linear, fused ----
    spmm1_gemm2_kernel<<<N_NODES / 4, 256, 0, stream>>>(row_ptr, pedge, xw, W2, hw);

    // ---- layer 2 aggregate ----
    {
        long long threads = (long long)N_NODES * 16;
        spmm2_kernel<<<(int)((threads + 255) / 256), 256, 0, stream>>>(
            row_ptr, pedge, hw, out);
    }
}

// Round 10
// 323.852 us; speedup vs baseline: 1.0988x; 1.0988x over previous
//
#include <hip/hip_runtime.h>
#include <hip/hip_bf16.h>

#define N_NODES 100000
#define IN_F 256
#define HID_F 128
#define OUT_F 32
#define NBUCK 391                  // buckets of 256 rows (row >> 8)
#define BCAP  5120                 // per-bucket staging capacity (mean 4092)
#define ACHUNK 4096                // edges per bucketize block
#define NCHUNKS ((1600000 + ACHUNK - 1) / ACHUNK)   // 391 for E=1.6M
#define GEMM1_BLOCKS ((N_NODES + 127) / 128)        // 782

typedef __bf16 bf16x8 __attribute__((ext_vector_type(8)));
typedef __bf16 bf16x4 __attribute__((ext_vector_type(4)));
typedef __bf16 bf16x2 __attribute__((ext_vector_type(2)));
typedef float  f32x4  __attribute__((ext_vector_type(4)));

// ---------------- W1 [256 k][128 n] f32 -> W1T [128 n][256 k] bf16 ----------------
__global__ void cvt_w1t_kernel(const float* __restrict__ W1, __bf16* __restrict__ W1T) {
    int i = blockIdx.x * 256 + threadIdx.x;      // i = n*256 + k
    if (i >= IN_F * HID_F) return;
    int n = i >> 8, k = i & 255;
    W1T[i] = (__bf16)W1[k * HID_F + n];
}

// ---------------- bucketize body (stage A of CSR build) ----------------
// smem: int2 lcv[4096] | lcnt/loff/lcur/gbase[NBUCK] | psum[256] = 40048 B
__device__ __forceinline__
void bucketize_body(char* smem, int blk,
                    const int* __restrict__ rows, const int* __restrict__ cols,
                    const float* __restrict__ vals, int* __restrict__ gcnt,
                    int2* __restrict__ staged, int E) {
    int2* lcv  = (int2*)smem;
    int* lcnt  = (int*)(smem + ACHUNK * 8);
    int* loff  = lcnt + NBUCK;
    int* lcur  = loff + NBUCK;
    int* gbase = lcur + NBUCK;
    int* psum  = gbase + NBUCK;

    const int t    = threadIdx.x;
    const int base = blk * ACHUNK;

    for (int b = t; b < NBUCK; b += 256) lcnt[b] = 0;
    __syncthreads();

    int myrow[16];
#pragma unroll
    for (int i = 0; i < 16; ++i) {
        int e = base + t + i * 256;
        int r = (e < E) ? rows[e] : -1;
        myrow[i] = r;
        if (r >= 0) atomicAdd(&lcnt[r >> 8], 1);
    }
    __syncthreads();

    int s0 = (t * 2     < NBUCK) ? lcnt[t * 2]     : 0;
    int s1 = (t * 2 + 1 < NBUCK) ? lcnt[t * 2 + 1] : 0;
    int local = s0 + s1;
    psum[t] = local;
    __syncthreads();
    for (int off = 1; off < 256; off <<= 1) {
        int v = (t >= off) ? psum[t - off] : 0;
        __syncthreads();
        psum[t] += v;
        __syncthreads();
    }
    int excl = psum[t] - local;
    if (t * 2     < NBUCK) { loff[t * 2]     = excl;      lcur[t * 2]     = excl; }
    if (t * 2 + 1 < NBUCK) { loff[t * 2 + 1] = excl + s0; lcur[t * 2 + 1] = excl + s0; }
    __syncthreads();

#pragma unroll
    for (int i = 0; i < 16; ++i) {
        int r = myrow[i];
        if (r >= 0) {
            int e = base + t + i * 256;
            int posl = atomicAdd(&lcur[r >> 8], 1);
            lcv[posl] = make_int2(cols[e] | ((r & 255) << 20), __float_as_int(vals[e]));
        }
    }
    __syncthreads();

    for (int b = t; b < NBUCK; b += 256) {
        int c = lcnt[b];
        gbase[b] = c ? atomicAdd(&gcnt[b], c) : 0;
    }
    __syncthreads();

    int total = loff[NBUCK - 1] + lcnt[NBUCK - 1];
    for (int i = t; i < total; i += 256) {
        int lo = 0, hi = NBUCK - 1;
        while (lo < hi) {
            int mid = (lo + hi + 1) >> 1;
            if (loff[mid] <= i) lo = mid; else hi = mid - 1;
        }
        int idx = gbase[lo] + (i - loff[lo]);
        if (idx < BCAP)
            staged[(size_t)lo * BCAP + idx] = lcv[i];
    }
}

// ---------------- gemm1 body (MFMA): xw_bf16 = bf16(x) @ bf16(W1) ----------------
// Round-3/4 proven structure: quarter-K tiles, both operands in LDS, [76] pad.
__device__ __forceinline__
void gemm1_body(char* smem, int blk,
                const float* __restrict__ x, const __bf16* __restrict__ W1T,
                __bf16* __restrict__ xw) {
    __bf16 (*Xs)[76] = (__bf16 (*)[76])smem;
    __bf16 (*Bs)[76] = (__bf16 (*)[76])(smem + 19456);
    __bf16 (*Ls)[136] = (__bf16 (*)[136])smem;   // epilogue tile (34816 B)

    const int r0   = blk * 128;
    const int t    = threadIdx.x;
    const int wv   = t >> 6;
    const int lane = t & 63;
    const int quad = lane >> 4;
    const int l15  = lane & 15;

    f32x4 acc[2][8];
#pragma unroll
    for (int rt = 0; rt < 2; ++rt)
#pragma unroll
        for (int nt = 0; nt < 8; ++nt)
            acc[rt][nt] = (f32x4){0.f, 0.f, 0.f, 0.f};

    const int srow = t >> 3;          // 0..31
    const int soct = t & 7;           // 0..7

    for (int q = 0; q < 4; ++q) {
        const int kq = q * 64;
#pragma unroll
        for (int j = 0; j < 4; ++j) {
            int row = j * 32 + srow;
            int gm = r0 + row;
            if (gm > N_NODES - 1) gm = N_NODES - 1;
            const float* xp = x + (size_t)gm * IN_F + kq + soct * 8;
            float4 f0 = *(const float4*)xp;
            float4 f1 = *(const float4*)(xp + 4);
            bf16x8 v = { (__bf16)f0.x, (__bf16)f0.y, (__bf16)f0.z, (__bf16)f0.w,
                         (__bf16)f1.x, (__bf16)f1.y, (__bf16)f1.z, (__bf16)f1.w };
            *(bf16x8*)(&Xs[row][soct * 8]) = v;
        }
#pragma unroll
        for (int i = 0; i < 4; ++i) {
            int idx = t + i * 256;            // 0..1023
            int n = idx >> 3, kc = idx & 7;
            bf16x8 w = *(const bf16x8*)(W1T + n * 256 + kq + kc * 8);
            *(bf16x8*)(&Bs[n][kc * 8]) = w;
        }
        __syncthreads();

#pragma unroll
        for (int kt = 0; kt < 2; ++kt) {
            const int k0 = kt * 32;
            bf16x8 a[2];
#pragma unroll
            for (int rt = 0; rt < 2; ++rt)
                a[rt] = *(const bf16x8*)(&Xs[wv * 32 + rt * 16 + l15][k0 + quad * 8]);
            bf16x8 b[8];
#pragma unroll
            for (int nt = 0; nt < 8; ++nt)
                b[nt] = *(const bf16x8*)(&Bs[nt * 16 + l15][k0 + quad * 8]);
#pragma unroll
            for (int rt = 0; rt < 2; ++rt)
#pragma unroll
                for (int nt = 0; nt < 8; ++nt)
                    acc[rt][nt] = __builtin_amdgcn_mfma_f32_16x16x32_bf16(
                        a[rt], b[nt], acc[rt][nt], 0, 0, 0);
        }
        __syncthreads();
    }

    // ---- epilogue: acc -> LDS (bf16) -> coalesced global stores ----
#pragma unroll
    for (int rt = 0; rt < 2; ++rt)
#pragma unroll
        for (int nt = 0; nt < 8; ++nt)
#pragma unroll
            for (int reg = 0; reg < 4; ++reg)
                Ls[wv * 32 + rt * 16 + quad * 4 + reg][nt * 16 + l15] =
                    (__bf16)acc[rt][nt][reg];
    __syncthreads();

#pragma unroll
    for (int i = 0; i < 8; ++i) {
        int id = i * 256 + t;                 // 0..2047
        int row = id >> 4, cc = id & 15;
        int g = r0 + row;
        if (g < N_NODES) {
            bf16x8 v = *(const bf16x8*)(&Ls[row][cc * 8]);
            *(bf16x8*)(xw + (size_t)g * HID_F + cc * 8) = v;
        }
    }
}

// ---------------- fused: bucketize (blocks 0..NCHUNKS-1) + gemm1 (rest) ----------------
__global__ __launch_bounds__(256, 4)
void fused_gemm1_bucketize_kernel(const float* __restrict__ x,
                                  const __bf16* __restrict__ W1T,
                                  __bf16* __restrict__ xw,
                                  const int* __restrict__ rows,
                                  const int* __restrict__ cols,
                                  const float* __restrict__ vals,
                                  int* __restrict__ gcnt,
                                  int2* __restrict__ staged, int E) {
    __shared__ __align__(16) char smem[40448];   // 4 blocks/CU
    if (blockIdx.x < NCHUNKS)
        bucketize_body(smem, blockIdx.x, rows, cols, vals, gcnt, staged, E);
    else
        gemm1_body(smem, blockIdx.x - NCHUNKS, x, W1T, xw);
}

// ---- per-bucket CSR finalize: inline scan of clamped gcnt + LDS counting sort ----
__global__ __launch_bounds__(256)
void bucket_csr_kernel(const int* __restrict__ gcnt,
                       const int2* __restrict__ staged,
                       int* __restrict__ row_ptr, int2* __restrict__ pedge) {
    __shared__ int2 lcv[BCAP];        // 40960 B
    __shared__ int lcnt[256], loff[256], lcur[256];
    __shared__ int psum[256];
    __shared__ int boff[NBUCK + 1];

    const int b = blockIdx.x;
    const int t = threadIdx.x;

    int c0 = (t * 2     < NBUCK) ? min(gcnt[t * 2],     BCAP) : 0;
    int c1 = (t * 2 + 1 < NBUCK) ? min(gcnt[t * 2 + 1], BCAP) : 0;
    int local = c0 + c1;
    psum[t] = local;
    __syncthreads();
    for (int off = 1; off < 256; off <<= 1) {
        int v = (t >= off) ? psum[t - off] : 0;
        __syncthreads();
        psum[t] += v;
        __syncthreads();
    }
    int excl = psum[t] - local;
    if (t * 2     < NBUCK)  boff[t * 2]     = excl;
    if (t * 2 + 1 <= NBUCK) boff[t * 2 + 1] = excl + c0;
    __syncthreads();

    int n = gcnt[b]; if (n > BCAP) n = BCAP;
    const int2* sp = staged + (size_t)b * BCAP;
    const int base = boff[b];

    if (b == NBUCK - 1 && t == 0) row_ptr[N_NODES] = boff[NBUCK];

    lcnt[t] = 0;
    __syncthreads();
    for (int i = t; i < n; i += 256) {
        int2 v = sp[i];
        lcv[i] = v;
        atomicAdd(&lcnt[(v.x >> 20) & 255], 1);
    }
    __syncthreads();

    int v = lcnt[t];
    loff[t] = v;
    __syncthreads();
    for (int off = 1; off < 256; off <<= 1) {
        int u = (t >= off) ? loff[t - off] : 0;
        __syncthreads();
        loff[t] += u;
        __syncthreads();
    }
    int excl2 = loff[t] - v;
    lcur[t] = excl2;
    __syncthreads();

    int row = (b << 8) + t;
    if (row < N_NODES) row_ptr[row] = base + excl2;

    for (int i = t; i < n; i += 256) {
        int2 cv = lcv[i];
        int r = (cv.x >> 20) & 255;
        int pos = atomicAdd(&lcur[r], 1);         // LDS cursor
        pedge[base + pos] = make_int2(cv.x & 0xFFFFF, cv.y);
    }
}

// ------- SpMM layer 1 + GEMM2 fused: hw = (relu(A @ xw)) @ bf16(W2) -------
// Gather engine = round-7 measured-best (88.6 us): full wave per row, lane owns
// feats (2l, 2l+1), 8 independent bf16x2 gathers in flight (MLP=8 -- round 9
// proved halving this to 4 costs +22 us; the kernel is gather-latency-bound).
// New vs R7: (a) clamp-free main loop + single clamped tail round;
// (b) h kept f32 in LDS; (c) W2T pad 132 (4-way max, was 8-way at 136).
__global__ __launch_bounds__(256)
void spmm1_gemm2_kernel(const int* __restrict__ row_ptr,
                        const int2* __restrict__ pedge,
                        const __bf16* __restrict__ src,
                        const float* __restrict__ W2,
                        __bf16* __restrict__ hw) {
    __shared__ __bf16 W2T[32][132];               // [out o][k] bf16
    __shared__ __align__(16) float hs[4][128];    // per-wave h row, f32

    const int t    = threadIdx.x;
    const int wv   = t >> 6;
    const int lane = t & 63;

    // stage W2T: consecutive lanes read consecutive W2 elements (coalesced)
    for (int i = t; i < 32 * 128; i += 256) {
        int o = i & 31, k = i >> 5;
        W2T[o][k] = (__bf16)W2[i];
    }
    __syncthreads();

    const int row = __builtin_amdgcn_readfirstlane(blockIdx.x * 4 + wv);
    const int e0 = row_ptr[row];
    const int e1 = row_ptr[row + 1];

    const bf16x2* srcl = (const bf16x2*)src;      // index: col*64 + lane

    float a0 = 0.f, a1 = 0.f;
    int e = e0;
    // ---- clamp-free full rounds ----
    for (; e + 8 <= e1; e += 8) {
        int2 p[8];
#pragma unroll
        for (int j = 0; j < 8; ++j) p[j] = pedge[e + j];
        bf16x2 s[8];
#pragma unroll
        for (int j = 0; j < 8; ++j)
            s[j] = srcl[(size_t)(unsigned)p[j].x * 64 + lane];
#pragma unroll
        for (int j = 0; j < 8; ++j) {
            float v = __int_as_float(p[j].y);
            a0 += v * (float)s[j].x;
            a1 += v * (float)s[j].y;
        }
    }
    // ---- single clamped tail round (0 < rem < 8) ----
    if (e < e1) {
        int2 p[8];
#pragma unroll
        for (int j = 0; j < 8; ++j) {
            int ee = e + j;
            if (ee >= e1) ee = e1 - 1;
            p[j] = pedge[ee];
            if (e + j >= e1) p[j].y = 0;
        }
        bf16x2 s[8];
#pragma unroll
        for (int j = 0; j < 8; ++j)
            s[j] = srcl[(size_t)(unsigned)p[j].x * 64 + lane];
#pragma unroll
        for (int j = 0; j < 8; ++j) {
            float v = __int_as_float(p[j].y);
            a0 += v * (float)s[j].x;
            a1 += v * (float)s[j].y;
        }
    }
    // relu + park f32 h row in LDS (lane owns feats 2*lane, 2*lane+1)
    float2 hv = make_float2(fmaxf(a0, 0.f), fmaxf(a1, 0.f));
    *(float2*)&hs[wv][lane * 2] = hv;
    __syncthreads();

    // ---- mini-GEMM: hw[row][o] = sum_k h[k] * W2[k][o]; lane = (o=q, k-half) ----
    const int q    = lane & 31;
    const int half = lane >> 5;
    const int kh   = half * 64;
    float s = 0.f;
#pragma unroll
    for (int kk = 0; kk < 64; kk += 4) {
        f32x4  hv4 = *(const f32x4*)&hs[wv][kh + kk];      // broadcast read
        bf16x4 w4  = *(const bf16x4*)&W2T[q][kh + kk];
        s += hv4[0] * (float)w4[0] + hv4[1] * (float)w4[1]
           + hv4[2] * (float)w4[2] + hv4[3] * (float)w4[3];
    }
    s += __shfl_xor(s, 32);
    if (half == 0)
        hw[(size_t)row * OUT_F + q] = (__bf16)s;
}

// ---------------- SpMM layer 2: out_f32 = A @ hw_bf16 ----------------
__global__ __launch_bounds__(256)
void spmm2_kernel(const int* __restrict__ row_ptr,
                  const int2* __restrict__ pedge,
                  const __bf16* __restrict__ src,
                  float* __restrict__ dst) {
    long long gid = (long long)blockIdx.x * 256 + threadIdx.x;
    int row  = (int)(gid >> 4);
    int lane = (int)(gid & 15);
    if (row >= N_NODES) return;

    const int e0 = row_ptr[row];
    const int e1 = row_ptr[row + 1];

    float a0 = 0.f, a1 = 0.f;
    for (int e = e0; e < e1; e += 8) {
        int2 p[8];
#pragma unroll
        for (int j = 0; j < 8; ++j) {
            int ee = e + j;
            if (ee >= e1) ee = e1 - 1;
            p[j] = pedge[ee];
            if (e + j >= e1) p[j].y = 0;
        }
        bf16x2 s[8];
#pragma unroll
        for (int j = 0; j < 8; ++j)
            s[j] = ((const bf16x2*)(src + (size_t)p[j].x * OUT_F))[lane];
#pragma unroll
        for (int j = 0; j < 8; ++j) {
            float v = __int_as_float(p[j].y);
            a0 += v * (float)s[j].x;
            a1 += v * (float)s[j].y;
        }
    }
    ((float2*)(dst + (size_t)row * OUT_F))[lane] = make_float2(a0, a1);
}

extern "C" void kernel_launch(void* const* d_in, const int* in_sizes, int n_in,
                              void* d_out, int out_size, void* d_ws, size_t ws_size,
                              hipStream_t stream) {
    const float* x        = (const float*)d_in[0];
    const int*   adj_rows = (const int*)d_in[1];
    const int*   adj_cols = (const int*)d_in[2];
    const float* adj_vals = (const float*)d_in[3];
    const float* W1       = (const float*)d_in[4];
    const float* W2       = (const float*)d_in[5];
    float*       out      = (float*)d_out;
    const int E = in_sizes[1];

    char* p = (char*)d_ws;
    __bf16* W1T  = (__bf16*)p;  p += (size_t)IN_F * HID_F * sizeof(__bf16);     // 64 KB
    __bf16* xw   = (__bf16*)p;  p += (size_t)N_NODES * HID_F * sizeof(__bf16);  // 25.6 MB
    __bf16* hw   = (__bf16*)p;  p += (size_t)N_NODES * OUT_F * sizeof(__bf16);  // 6.4 MB
    int*   row_ptr = (int*)p;   p += (size_t)(N_NODES + 1) * sizeof(int);
    int*   gcnt    = (int*)p;   p += ((NBUCK + 255) & ~255) * sizeof(int);
    p = (char*)(((uintptr_t)p + 15) & ~(uintptr_t)15);
    int2*  pedge   = (int2*)p;  p += (size_t)E * sizeof(int2);                  // 12.8 MB
    p = (char*)(((uintptr_t)p + 15) & ~(uintptr_t)15);
    int2*  staged  = (int2*)p;  p += (size_t)NBUCK * BCAP * sizeof(int2);       // 16.0 MB

    // ---- prep ----
    hipMemsetAsync(gcnt, 0, (size_t)NBUCK * sizeof(int), stream);
    cvt_w1t_kernel<<<(IN_F * HID_F + 255) / 256, 256, 0, stream>>>(W1, W1T);

    // ---- fused: CSR stage-A (391 blocks) + gemm1 (782 blocks) ----
    fused_gemm1_bucketize_kernel<<<NCHUNKS + GEMM1_BLOCKS, 256, 0, stream>>>(
        x, W1T, xw, adj_rows, adj_cols, adj_vals, gcnt, staged, E);

    // ---- CSR finalize (scan fused into bucket_csr) ----
    bucket_csr_kernel<<<NBUCK, 256, 0, stream>>>(gcnt, staged, row_ptr, pedge);

    // ---- layer 1 aggregate + layer-2 linear, fused ----
    spmm1_gemm2_kernel<<<N_NODES / 4, 256, 0, stream>>>(row_ptr, pedge, xw, W2, hw);

    // ---- layer 2 aggregate ----
    {
        long long threads = (long long)N_NODES * 16;
        spmm2_kernel<<<(int)((threads + 255) / 256), 256, 0, stream>>>(
            row_ptr, pedge, hw, out);
    }
}

// Round 14
// 317.257 us; speedup vs baseline: 1.1216x; 1.0208x over previous
//
#include <hip/hip_runtime.h>
#include <hip/hip_bf16.h>

#define N_NODES 100000
#define IN_F 256
#define HID_F 128
#define OUT_F 32
#define NBUCK 391                  // buckets of 256 rows (row >> 8)
#define BCAP  5120                 // per-bucket staging capacity (mean 4092)
#define ACHUNK 4096                // edges per bucketize block
#define NCHUNKS ((1600000 + ACHUNK - 1) / ACHUNK)   // 391 for E=1.6M
#define GEMM1_BLOCKS ((N_NODES + 127) / 128)        // 782

typedef __bf16 bf16x8 __attribute__((ext_vector_type(8)));
typedef __bf16 bf16x4 __attribute__((ext_vector_type(4)));
typedef __bf16 bf16x2 __attribute__((ext_vector_type(2)));
typedef float  f32x4  __attribute__((ext_vector_type(4)));

// ---------------- W1 [256 k][128 n] f32 -> W1T [128 n][256 k] bf16 ----------------
__global__ void cvt_w1t_kernel(const float* __restrict__ W1, __bf16* __restrict__ W1T) {
    int i = blockIdx.x * 256 + threadIdx.x;      // i = n*256 + k
    if (i >= IN_F * HID_F) return;
    int n = i >> 8, k = i & 255;
    W1T[i] = (__bf16)W1[k * HID_F + n];
}

// ---------------- bucketize body (stage A of CSR build) ----------------
// smem: int2 lcv[4096] | lcnt/loff/lcur/gbase[NBUCK] | psum[256] = 40048 B
__device__ __forceinline__
void bucketize_body(char* smem, int blk,
                    const int* __restrict__ rows, const int* __restrict__ cols,
                    const float* __restrict__ vals, int* __restrict__ gcnt,
                    int2* __restrict__ staged, int E) {
    int2* lcv  = (int2*)smem;
    int* lcnt  = (int*)(smem + ACHUNK * 8);
    int* loff  = lcnt + NBUCK;
    int* lcur  = loff + NBUCK;
    int* gbase = lcur + NBUCK;
    int* psum  = gbase + NBUCK;

    const int t    = threadIdx.x;
    const int base = blk * ACHUNK;

    for (int b = t; b < NBUCK; b += 256) lcnt[b] = 0;
    __syncthreads();

    int myrow[16];
#pragma unroll
    for (int i = 0; i < 16; ++i) {
        int e = base + t + i * 256;
        int r = (e < E) ? rows[e] : -1;
        myrow[i] = r;
        if (r >= 0) atomicAdd(&lcnt[r >> 8], 1);
    }
    __syncthreads();

    int s0 = (t * 2     < NBUCK) ? lcnt[t * 2]     : 0;
    int s1 = (t * 2 + 1 < NBUCK) ? lcnt[t * 2 + 1] : 0;
    int local = s0 + s1;
    psum[t] = local;
    __syncthreads();
    for (int off = 1; off < 256; off <<= 1) {
        int v = (t >= off) ? psum[t - off] : 0;
        __syncthreads();
        psum[t] += v;
        __syncthreads();
    }
    int excl = psum[t] - local;
    if (t * 2     < NBUCK) { loff[t * 2]     = excl;      lcur[t * 2]     = excl; }
    if (t * 2 + 1 < NBUCK) { loff[t * 2 + 1] = excl + s0; lcur[t * 2 + 1] = excl + s0; }
    __syncthreads();

#pragma unroll
    for (int i = 0; i < 16; ++i) {
        int r = myrow[i];
        if (r >= 0) {
            int e = base + t + i * 256;
            int posl = atomicAdd(&lcur[r >> 8], 1);
            lcv[posl] = make_int2(cols[e] | ((r & 255) << 20), __float_as_int(vals[e]));
        }
    }
    __syncthreads();

    for (int b = t; b < NBUCK; b += 256) {
        int c = lcnt[b];
        gbase[b] = c ? atomicAdd(&gcnt[b], c) : 0;
    }
    __syncthreads();

    int total = loff[NBUCK - 1] + lcnt[NBUCK - 1];
    for (int i = t; i < total; i += 256) {
        int lo = 0, hi = NBUCK - 1;
        while (lo < hi) {
            int mid = (lo + hi + 1) >> 1;
            if (loff[mid] <= i) lo = mid; else hi = mid - 1;
        }
        int idx = gbase[lo] + (i - loff[lo]);
        if (idx < BCAP)
            staged[(size_t)lo * BCAP + idx] = lcv[i];
    }
}

// ---------------- gemm1 body (MFMA): xw_bf16 = bf16(x) @ bf16(W1) ----------------
// Round-10 measured config (79.8 us): quarter-K tiles, both operands in LDS,
// [76] pad, plain float4 x loads. (nt-load experiment deferred: two container
// failures on that source; this round isolates the unfuse.)
__device__ __forceinline__
void gemm1_body(char* smem, int blk,
                const float* __restrict__ x, const __bf16* __restrict__ W1T,
                __bf16* __restrict__ xw) {
    __bf16 (*Xs)[76] = (__bf16 (*)[76])smem;
    __bf16 (*Bs)[76] = (__bf16 (*)[76])(smem + 19456);
    __bf16 (*Ls)[136] = (__bf16 (*)[136])smem;   // epilogue tile (34816 B)

    const int r0   = blk * 128;
    const int t    = threadIdx.x;
    const int wv   = t >> 6;
    const int lane = t & 63;
    const int quad = lane >> 4;
    const int l15  = lane & 15;

    f32x4 acc[2][8];
#pragma unroll
    for (int rt = 0; rt < 2; ++rt)
#pragma unroll
        for (int nt = 0; nt < 8; ++nt)
            acc[rt][nt] = (f32x4){0.f, 0.f, 0.f, 0.f};

    const int srow = t >> 3;          // 0..31
    const int soct = t & 7;           // 0..7

    for (int q = 0; q < 4; ++q) {
        const int kq = q * 64;
#pragma unroll
        for (int j = 0; j < 4; ++j) {
            int row = j * 32 + srow;
            int gm = r0 + row;
            if (gm > N_NODES - 1) gm = N_NODES - 1;
            const float* xp = x + (size_t)gm * IN_F + kq + soct * 8;
            float4 f0 = *(const float4*)xp;
            float4 f1 = *(const float4*)(xp + 4);
            bf16x8 v = { (__bf16)f0.x, (__bf16)f0.y, (__bf16)f0.z, (__bf16)f0.w,
                         (__bf16)f1.x, (__bf16)f1.y, (__bf16)f1.z, (__bf16)f1.w };
            *(bf16x8*)(&Xs[row][soct * 8]) = v;
        }
#pragma unroll
        for (int i = 0; i < 4; ++i) {
            int idx = t + i * 256;            // 0..1023
            int n = idx >> 3, kc = idx & 7;
            bf16x8 w = *(const bf16x8*)(W1T + n * 256 + kq + kc * 8);
            *(bf16x8*)(&Bs[n][kc * 8]) = w;
        }
        __syncthreads();

#pragma unroll
        for (int kt = 0; kt < 2; ++kt) {
            const int k0 = kt * 32;
            bf16x8 a[2];
#pragma unroll
            for (int rt = 0; rt < 2; ++rt)
                a[rt] = *(const bf16x8*)(&Xs[wv * 32 + rt * 16 + l15][k0 + quad * 8]);
            bf16x8 b[8];
#pragma unroll
            for (int nt = 0; nt < 8; ++nt)
                b[nt] = *(const bf16x8*)(&Bs[nt * 16 + l15][k0 + quad * 8]);
#pragma unroll
            for (int rt = 0; rt < 2; ++rt)
#pragma unroll
                for (int nt = 0; nt < 8; ++nt)
                    acc[rt][nt] = __builtin_amdgcn_mfma_f32_16x16x32_bf16(
                        a[rt], b[nt], acc[rt][nt], 0, 0, 0);
        }
        __syncthreads();
    }

    // ---- epilogue: acc -> LDS (bf16) -> coalesced global stores ----
#pragma unroll
    for (int rt = 0; rt < 2; ++rt)
#pragma unroll
        for (int nt = 0; nt < 8; ++nt)
#pragma unroll
            for (int reg = 0; reg < 4; ++reg)
                Ls[wv * 32 + rt * 16 + quad * 4 + reg][nt * 16 + l15] =
                    (__bf16)acc[rt][nt][reg];
    __syncthreads();

#pragma unroll
    for (int i = 0; i < 8; ++i) {
        int id = i * 256 + t;                 // 0..2047
        int row = id >> 4, cc = id & 15;
        int g = r0 + row;
        if (g < N_NODES) {
            bf16x8 v = *(const bf16x8*)(&Ls[row][cc * 8]);
            *(bf16x8*)(xw + (size_t)g * HID_F + cc * 8) = v;
        }
    }
}

// ---------------- fused: bucketize (blocks 0..NCHUNKS-1) + gemm1 (rest) ----------------
__global__ __launch_bounds__(256, 4)
void fused_gemm1_bucketize_kernel(const float* __restrict__ x,
                                  const __bf16* __restrict__ W1T,
                                  __bf16* __restrict__ xw,
                                  const int* __restrict__ rows,
                                  const int* __restrict__ cols,
                                  const float* __restrict__ vals,
                                  int* __restrict__ gcnt,
                                  int2* __restrict__ staged, int E) {
    __shared__ __align__(16) char smem[40448];   // 4 blocks/CU
    if (blockIdx.x < NCHUNKS)
        bucketize_body(smem, blockIdx.x, rows, cols, vals, gcnt, staged, E);
    else
        gemm1_body(smem, blockIdx.x - NCHUNKS, x, W1T, xw);
}

// ---- per-bucket CSR finalize: inline scan of clamped gcnt + LDS counting sort ----
__global__ __launch_bounds__(256)
void bucket_csr_kernel(const int* __restrict__ gcnt,
                       const int2* __restrict__ staged,
                       int* __restrict__ row_ptr, int2* __restrict__ pedge) {
    __shared__ int2 lcv[BCAP];        // 40960 B
    __shared__ int lcnt[256], loff[256], lcur[256];
    __shared__ int psum[256];
    __shared__ int boff[NBUCK + 1];

    const int b = blockIdx.x;
    const int t = threadIdx.x;

    int c0 = (t * 2     < NBUCK) ? min(gcnt[t * 2],     BCAP) : 0;
    int c1 = (t * 2 + 1 < NBUCK) ? min(gcnt[t * 2 + 1], BCAP) : 0;
    int local = c0 + c1;
    psum[t] = local;
    __syncthreads();
    for (int off = 1; off < 256; off <<= 1) {
        int v = (t >= off) ? psum[t - off] : 0;
        __syncthreads();
        psum[t] += v;
        __syncthreads();
    }
    int excl = psum[t] - local;
    if (t * 2     < NBUCK)  boff[t * 2]     = excl;
    if (t * 2 + 1 <= NBUCK) boff[t * 2 + 1] = excl + c0;
    __syncthreads();

    int n = gcnt[b]; if (n > BCAP) n = BCAP;
    const int2* sp = staged + (size_t)b * BCAP;
    const int base = boff[b];

    if (b == NBUCK - 1 && t == 0) row_ptr[N_NODES] = boff[NBUCK];

    lcnt[t] = 0;
    __syncthreads();
    for (int i = t; i < n; i += 256) {
        int2 v = sp[i];
        lcv[i] = v;
        atomicAdd(&lcnt[(v.x >> 20) & 255], 1);
    }
    __syncthreads();

    int v = lcnt[t];
    loff[t] = v;
    __syncthreads();
    for (int off = 1; off < 256; off <<= 1) {
        int u = (t >= off) ? loff[t - off] : 0;
        __syncthreads();
        loff[t] += u;
        __syncthreads();
    }
    int excl2 = loff[t] - v;
    lcur[t] = excl2;
    __syncthreads();

    int row = (b << 8) + t;
    if (row < N_NODES) row_ptr[row] = base + excl2;

    for (int i = t; i < n; i += 256) {
        int2 cv = lcv[i];
        int r = (cv.x >> 20) & 255;
        int pos = atomicAdd(&lcur[r], 1);         // LDS cursor
        pedge[base + pos] = make_int2(cv.x & 0xFFFFF, cv.y);
    }
}

// ---------------- SpMM layer 1: h_bf16 = relu(A @ xw_bf16) ----------------
// One wave per row, lane owns feats (2l, 2l+1), 8 gathers in flight.
// Clamp-free main loop + single clamped tail (round-10 improvement, kept).
// No LDS, no W2 staging (unfused from gemm2: 25000-block W2 restage = 400 MB).
__global__ __launch_bounds__(256)
void spmm1_kernel(const int* __restrict__ row_ptr,
                  const int2* __restrict__ pedge,
                  const __bf16* __restrict__ src,
                  __bf16* __restrict__ dst) {
    const int wv   = threadIdx.x >> 6;
    const int lane = threadIdx.x & 63;
    const int row  = __builtin_amdgcn_readfirstlane(blockIdx.x * 4 + wv);
    if (row >= N_NODES) return;

    const int e0 = row_ptr[row];
    const int e1 = row_ptr[row + 1];

    const bf16x2* srcl = (const bf16x2*)src;      // index: col*64 + lane

    float a0 = 0.f, a1 = 0.f;
    int e = e0;
    for (; e + 8 <= e1; e += 8) {
        int2 p[8];
#pragma unroll
        for (int j = 0; j < 8; ++j) p[j] = pedge[e + j];
        bf16x2 s[8];
#pragma unroll
        for (int j = 0; j < 8; ++j)
            s[j] = srcl[(size_t)(unsigned)p[j].x * 64 + lane];
#pragma unroll
        for (int j = 0; j < 8; ++j) {
            float v = __int_as_float(p[j].y);
            a0 += v * (float)s[j].x;
            a1 += v * (float)s[j].y;
        }
    }
    if (e < e1) {
        int2 p[8];
#pragma unroll
        for (int j = 0; j < 8; ++j) {
            int ee = e + j;
            if (ee >= e1) ee = e1 - 1;
            p[j] = pedge[ee];
            if (e + j >= e1) p[j].y = 0;
        }
        bf16x2 s[8];
#pragma unroll
        for (int j = 0; j < 8; ++j)
            s[j] = srcl[(size_t)(unsigned)p[j].x * 64 + lane];
#pragma unroll
        for (int j = 0; j < 8; ++j) {
            float v = __int_as_float(p[j].y);
            a0 += v * (float)s[j].x;
            a1 += v * (float)s[j].y;
        }
    }
    bf16x2 o = { (__bf16)fmaxf(a0, 0.f), (__bf16)fmaxf(a1, 0.f) };   // fused relu
    ((bf16x2*)(dst + (size_t)row * HID_F))[lane] = o;
}

// ---------------- GEMM2 (MFMA): hw_bf16 = h_bf16 @ bf16(W2) ----------------
__global__ __launch_bounds__(256)
void gemm2_mfma_kernel(const __bf16* __restrict__ h,
                       const float* __restrict__ W2,
                       __bf16* __restrict__ hw) {
    const int r0   = blockIdx.x * 128;
    const int wv   = threadIdx.x >> 6;
    const int lane = threadIdx.x & 63;
    const int quad = lane >> 4;
    const int l15  = lane & 15;

    __shared__ __bf16 W2T[32][132];

    for (int i = threadIdx.x; i < 32 * 128; i += 256) {
        int n = i & 31, k = i >> 5;
        W2T[n][k] = (__bf16)W2[k * OUT_F + n];
    }
    __syncthreads();

    f32x4 acc[2][2];
#pragma unroll
    for (int rt = 0; rt < 2; ++rt)
#pragma unroll
        for (int nt = 0; nt < 2; ++nt)
            acc[rt][nt] = (f32x4){0.f, 0.f, 0.f, 0.f};

#pragma unroll
    for (int kt = 0; kt < 4; ++kt) {
        const int k0 = kt * 32;
        bf16x8 a[2];
#pragma unroll
        for (int rt = 0; rt < 2; ++rt) {
            int gm = r0 + wv * 32 + rt * 16 + l15;
            if (gm > N_NODES - 1) gm = N_NODES - 1;
            a[rt] = *(const bf16x8*)(h + (size_t)gm * HID_F + k0 + quad * 8);
        }
        bf16x8 b[2];
#pragma unroll
        for (int nt = 0; nt < 2; ++nt)
            b[nt] = *(const bf16x8*)(&W2T[nt * 16 + l15][k0 + quad * 8]);
#pragma unroll
        for (int rt = 0; rt < 2; ++rt)
#pragma unroll
            for (int nt = 0; nt < 2; ++nt)
                acc[rt][nt] = __builtin_amdgcn_mfma_f32_16x16x32_bf16(
                    a[rt], b[nt], acc[rt][nt], 0, 0, 0);
    }

#pragma unroll
    for (int rt = 0; rt < 2; ++rt)
#pragma unroll
        for (int nt = 0; nt < 2; ++nt)
#pragma unroll
            for (int reg = 0; reg < 4; ++reg) {
                int row = r0 + wv * 32 + rt * 16 + quad * 4 + reg;
                if (row < N_NODES)
                    hw[(size_t)row * OUT_F + nt * 16 + l15] = (__bf16)acc[rt][nt][reg];
            }
}

// ---------------- SpMM layer 2: out_f32 = A @ hw_bf16 ----------------
__global__ __launch_bounds__(256)
void spmm2_kernel(const int* __restrict__ row_ptr,
                  const int2* __restrict__ pedge,
                  const __bf16* __restrict__ src,
                  float* __restrict__ dst) {
    long long gid = (long long)blockIdx.x * 256 + threadIdx.x;
    int row  = (int)(gid >> 4);
    int lane = (int)(gid & 15);
    if (row >= N_NODES) return;

    const int e0 = row_ptr[row];
    const int e1 = row_ptr[row + 1];

    float a0 = 0.f, a1 = 0.f;
    for (int e = e0; e < e1; e += 8) {
        int2 p[8];
#pragma unroll
        for (int j = 0; j < 8; ++j) {
            int ee = e + j;
            if (ee >= e1) ee = e1 - 1;
            p[j] = pedge[ee];
            if (e + j >= e1) p[j].y = 0;
        }
        bf16x2 s[8];
#pragma unroll
        for (int j = 0; j < 8; ++j)
            s[j] = ((const bf16x2*)(src + (size_t)p[j].x * OUT_F))[lane];
#pragma unroll
        for (int j = 0; j < 8; ++j) {
            float v = __int_as_float(p[j].y);
            a0 += v * (float)s[j].x;
            a1 += v * (float)s[j].y;
        }
    }
    ((float2*)(dst + (size_t)row * OUT_F))[lane] = make_float2(a0, a1);
}

extern "C" void kernel_launch(void* const* d_in, const int* in_sizes, int n_in,
                              void* d_out, int out_size, void* d_ws, size_t ws_size,
                              hipStream_t stream) {
    const float* x        = (const float*)d_in[0];
    const int*   adj_rows = (const int*)d_in[1];
    const int*   adj_cols = (const int*)d_in[2];
    const float* adj_vals = (const float*)d_in[3];
    const float* W1       = (const float*)d_in[4];
    const float* W2       = (const float*)d_in[5];
    float*       out      = (float*)d_out;
    const int E = in_sizes[1];

    char* p = (char*)d_ws;
    __bf16* W1T  = (__bf16*)p;  p += (size_t)IN_F * HID_F * sizeof(__bf16);     // 64 KB
    __bf16* xw   = (__bf16*)p;  p += (size_t)N_NODES * HID_F * sizeof(__bf16);  // 25.6 MB
    __bf16* h    = (__bf16*)p;  p += (size_t)N_NODES * HID_F * sizeof(__bf16);  // 25.6 MB
    __bf16* hw   = (__bf16*)p;  p += (size_t)N_NODES * OUT_F * sizeof(__bf16);  // 6.4 MB
    int*   row_ptr = (int*)p;   p += (size_t)(N_NODES + 1) * sizeof(int);
    int*   gcnt    = (int*)p;   p += ((NBUCK + 255) & ~255) * sizeof(int);
    p = (char*)(((uintptr_t)p + 15) & ~(uintptr_t)15);
    int2*  pedge   = (int2*)p;  p += (size_t)E * sizeof(int2);                  // 12.8 MB
    p = (char*)(((uintptr_t)p + 15) & ~(uintptr_t)15);
    int2*  staged  = (int2*)p;  p += (size_t)NBUCK * BCAP * sizeof(int2);       // 16.0 MB

    // ---- prep ----
    hipMemsetAsync(gcnt, 0, (size_t)NBUCK * sizeof(int), stream);
    cvt_w1t_kernel<<<(IN_F * HID_F + 255) / 256, 256, 0, stream>>>(W1, W1T);

    // ---- fused: CSR stage-A (391 blocks) + gemm1 (782 blocks) ----
    fused_gemm1_bucketize_kernel<<<NCHUNKS + GEMM1_BLOCKS, 256, 0, stream>>>(
        x, W1T, xw, adj_rows, adj_cols, adj_vals, gcnt, staged, E);

    // ---- CSR finalize (scan fused into bucket_csr) ----
    bucket_csr_kernel<<<NBUCK, 256, 0, stream>>>(gcnt, staged, row_ptr, pedge);

    // ---- layer 1 aggregate ----
    spmm1_kernel<<<(N_NODES + 3) / 4, 256, 0, stream>>>(row_ptr, pedge, xw, h);

    // ---- layer 2 ----
    gemm2_mfma_kernel<<<(N_NODES + 127) / 128, 256, 0, stream>>>(h, W2, hw);
    {
        long long threads = (long long)N_NODES * 16;
        spmm2_kernel<<<(int)((threads + 255) / 256), 256, 0, stream>>>(
            row_ptr, pedge, hw, out);
    }
}